// Round 1
// baseline (1519.646 us; speedup 1.0000x reference)
//
#include <hip/hip_runtime.h>
#include <hip/hip_bf16.h>

typedef __attribute__((ext_vector_type(8))) short bf16x8;
typedef __attribute__((ext_vector_type(4))) short short4v;
typedef __attribute__((ext_vector_type(4))) float f32x4;

#define NE_      100000
#define EDIM     768
#define HALFCB   50000
#define CHK      1024
#define NCH      49
#define NQT      12
#define QS       1536
#define KTOP     10

// ws byte offsets
#define RN_OFF   0ULL
#define Q_OFF    401408ULL
#define Y_OFF    3547136ULL
#define ZF_OFF   6692864ULL
#define PT_OFF   9838592ULL
#define PG_OFF   11411456ULL
#define CAND_OFF 12984320ULL
#define APP_OFF  25026560ULL
#define FLAG_OFF 25108480ULL
#define CNT_OFF  26308480ULL
#define ACC_OFF  26308544ULL
#define WS_NEED  26308608ULL

// output element offsets (fp32)
#define O_ZQT    786432u
#define O_ZQG    1179648u
#define O_SVQ    1572864u
#define O_SQT    1572866u
#define O_SVQT   1966082u
#define O_SQG    1966084u
#define O_SVQG   2359300u
#define O_USE    2359302u

__device__ __forceinline__ short f2bf(float f) {
  union { float f; unsigned u; } v; v.f = f;
  unsigned r = v.u + 0x7FFFu + ((v.u >> 16) & 1u);
  return (short)(r >> 16);
}

__device__ __forceinline__ void ins10(float v, int idx, float s[10], int id[10]) {
  if (v <= s[0]) return;
  #pragma unroll
  for (int j = 0; j < 10; ++j) {
    bool shift = (j < 9) && (v > s[j + 1]);
    float ns = shift ? s[j + 1] : v;
    int   ni = shift ? id[j + 1] : idx;
    bool upd = shift || (v > s[j]);
    s[j]  = upd ? ns : s[j];
    id[j] = upd ? ni : id[j];
  }
}

// ---- codebook row rnorm: 1/max(||row||,1e-12) ----
__global__ __launch_bounds__(256) void k_rnorm(const float* __restrict__ cb, float* __restrict__ rn) {
  int row = blockIdx.x * 4 + (threadIdx.x >> 6);
  int lane = threadIdx.x & 63;
  const float4* p = (const float4*)(cb + (size_t)row * EDIM);
  float ss = 0.f;
  #pragma unroll
  for (int j = 0; j < 3; ++j) {
    float4 v = p[j * 64 + lane];
    ss += v.x * v.x + v.y * v.y + v.z * v.z + v.w * v.w;
  }
  #pragma unroll
  for (int off = 32; off; off >>= 1) ss += __shfl_xor(ss, off);
  if (lane == 0) rn[row] = 1.0f / fmaxf(sqrtf(ss), 1e-12f);
}

// ---- out0 = z[:,768:], out1 = z[:,:768] ----
__global__ __launch_bounds__(256) void k_copyz(const float* __restrict__ z, float* __restrict__ out) {
  int i = blockIdx.x * 256 + threadIdx.x;   // < 98304 = 512*192
  int r = i / 192, c = i - r * 192;
  const float4* zr = (const float4*)z + (size_t)r * 384;
  float4 t = zr[c];
  float4 g = zr[192 + c];
  ((float4*)out)[i] = g;
  ((float4*)(out + 393216))[i] = t;
}

// ---- generic C = A @ W^T + bias, fp32 in/out, bf16 MFMA, tiles 128x128, K=768 ----
__global__ __launch_bounds__(256, 2) void k_gemm_proj(
    const float* __restrict__ A, int lda, const float* __restrict__ W,
    const float* __restrict__ bias, float* __restrict__ C) {
  __shared__ short As[128][72];
  __shared__ short Bs[128][72];
  int tid = threadIdx.x;
  int wave = tid >> 6, lane = tid & 63;
  int wr = wave >> 1, wc = wave & 1;
  int r16 = lane & 15, g8 = (lane >> 4) * 8;
  int m0 = blockIdx.x * 128, n0 = blockIdx.y * 128;
  f32x4 acc[4][4];
  f32x4 zv = {0.f, 0.f, 0.f, 0.f};
  #pragma unroll
  for (int m = 0; m < 4; ++m)
    #pragma unroll
    for (int n = 0; n < 4; ++n) acc[m][n] = zv;

  for (int ks = 0; ks < 12; ++ks) {
    float4 av[8], wv[8];
    #pragma unroll
    for (int i = 0; i < 8; ++i) {
      int id = i * 256 + tid;
      int r = id >> 4, c4 = id & 15;
      av[i] = *((const float4*)(A + (size_t)(m0 + r) * lda + ks * 64) + c4);
      wv[i] = *((const float4*)(W + (size_t)(n0 + r) * EDIM + ks * 64) + c4);
    }
    __syncthreads();
    #pragma unroll
    for (int i = 0; i < 8; ++i) {
      int id = i * 256 + tid;
      int r = id >> 4, c4 = id & 15;
      short4v sa = { f2bf(av[i].x), f2bf(av[i].y), f2bf(av[i].z), f2bf(av[i].w) };
      short4v sw = { f2bf(wv[i].x), f2bf(wv[i].y), f2bf(wv[i].z), f2bf(wv[i].w) };
      *(short4v*)&As[r][c4 * 4] = sa;
      *(short4v*)&Bs[r][c4 * 4] = sw;
    }
    __syncthreads();
    #pragma unroll
    for (int kk = 0; kk < 64; kk += 32) {
      bf16x8 a[4], b[4];
      #pragma unroll
      for (int m = 0; m < 4; ++m) a[m] = *(const bf16x8*)&As[wr * 64 + m * 16 + r16][kk + g8];
      #pragma unroll
      for (int n = 0; n < 4; ++n) b[n] = *(const bf16x8*)&Bs[wc * 64 + n * 16 + r16][kk + g8];
      #pragma unroll
      for (int m = 0; m < 4; ++m)
        #pragma unroll
        for (int n = 0; n < 4; ++n)
          acc[m][n] = __builtin_amdgcn_mfma_f32_16x16x32_bf16(a[m], b[n], acc[m][n], 0, 0, 0);
    }
  }
  #pragma unroll
  for (int n = 0; n < 4; ++n) {
    int col = n0 + wc * 64 + n * 16 + r16;
    float bb = bias[col];
    #pragma unroll
    for (int m = 0; m < 4; ++m) {
      int row = m0 + wr * 64 + m * 16 + (lane >> 4) * 4;
      #pragma unroll
      for (int j = 0; j < 4; ++j)
        C[(size_t)(row + j) * EDIM + col] = acc[m][n][j] + bb;
    }
  }
}

// ---- normalize 2048 query rows -> bf16 Q ----
__global__ __launch_bounds__(256) void k_normq(
    const float* __restrict__ ZF, const float* __restrict__ PT,
    const float* __restrict__ PG, short* __restrict__ Q) {
  int row = blockIdx.x * 4 + (threadIdx.x >> 6);
  int lane = threadIdx.x & 63;
  const float* src = (row < 1024) ? ZF + (size_t)row * EDIM
                   : (row < 1536) ? PT + (size_t)(row - 1024) * EDIM
                                  : PG + (size_t)(row - 1536) * EDIM;
  const float4* p = (const float4*)src;
  float4 v[3];
  float ss = 0.f;
  #pragma unroll
  for (int j = 0; j < 3; ++j) {
    v[j] = p[j * 64 + lane];
    ss += v[j].x * v[j].x + v[j].y * v[j].y + v[j].z * v[j].z + v[j].w * v[j].w;
  }
  #pragma unroll
  for (int off = 32; off; off >>= 1) ss += __shfl_xor(ss, off);
  float r = 1.0f / fmaxf(sqrtf(ss), 1e-12f);
  #pragma unroll
  for (int j = 0; j < 3; ++j) {
    short4v s = { f2bf(v[j].x * r), f2bf(v[j].y * r), f2bf(v[j].z * r), f2bf(v[j].w * r) };
    *(short4v*)(Q + (size_t)row * EDIM + (size_t)(j * 64 + lane) * 4) = s;
  }
}

// ---- main: scores + per-chunk top-10 ----
__global__ __launch_bounds__(256, 2) void k_scores(
    const float* __restrict__ cb, const float* __restrict__ rn,
    const short* __restrict__ Q, float2* __restrict__ cand) {
  __shared__ short As[128][72];
  __shared__ short Bs[128][72];
  __shared__ float Sc[128][65];
  int qt = blockIdx.x, ck = blockIdx.y, hh = blockIdx.z;
  int tid = threadIdx.x;
  int wave = tid >> 6, lane = tid & 63;
  int wr = wave >> 1, wc = wave & 1;
  int r16 = lane & 15, g8 = (lane >> 4) * 8;
  int row0 = ck * CHK;
  int nvalid = min(CHK, HALFCB - row0);
  int grow0 = hh * HALFCB + row0;
  int hmax = hh * HALFCB + HALFCB - 1;
  int qbase = qt * 128;
  int q = tid & 127, seg = tid >> 7;

  float s10[10]; int id10[10];
  #pragma unroll
  for (int k = 0; k < 10; ++k) { s10[k] = -3.4e38f; id10[k] = 0; }

  for (int mt = 0; mt < 8; ++mt) {
    f32x4 acc[4][4];
    f32x4 zv = {0.f, 0.f, 0.f, 0.f};
    #pragma unroll
    for (int m = 0; m < 4; ++m)
      #pragma unroll
      for (int n = 0; n < 4; ++n) acc[m][n] = zv;

    for (int ks = 0; ks < 12; ++ks) {
      float4 av[8]; float rsv[8]; uint4 qv[4];
      #pragma unroll
      for (int i = 0; i < 8; ++i) {
        int id = i * 256 + tid;
        int r = id >> 4, c4 = id & 15;
        int gr = grow0 + mt * 128 + r;
        gr = min(gr, hmax);
        av[i] = *((const float4*)(cb + (size_t)gr * EDIM + ks * 64) + c4);
        rsv[i] = rn[gr];
      }
      #pragma unroll
      for (int i = 0; i < 4; ++i) {
        int id = i * 256 + tid;
        int s = id >> 3, c8 = id & 7;
        int slot = qbase + s;
        int qr = (hh && slot >= 1024) ? slot + 512 : slot;
        qv[i] = *((const uint4*)(Q + (size_t)qr * EDIM + ks * 64) + c8);
      }
      __syncthreads();
      #pragma unroll
      for (int i = 0; i < 8; ++i) {
        int id = i * 256 + tid;
        int r = id >> 4, c4 = id & 15;
        short4v sa = { f2bf(av[i].x * rsv[i]), f2bf(av[i].y * rsv[i]),
                       f2bf(av[i].z * rsv[i]), f2bf(av[i].w * rsv[i]) };
        *(short4v*)&As[r][c4 * 4] = sa;
      }
      #pragma unroll
      for (int i = 0; i < 4; ++i) {
        int id = i * 256 + tid;
        int s = id >> 3, c8 = id & 7;
        *(uint4*)&Bs[s][c8 * 8] = qv[i];
      }
      __syncthreads();
      #pragma unroll
      for (int kk = 0; kk < 64; kk += 32) {
        bf16x8 a[4], b[4];
        #pragma unroll
        for (int m = 0; m < 4; ++m) a[m] = *(const bf16x8*)&As[wr * 64 + m * 16 + r16][kk + g8];
        #pragma unroll
        for (int n = 0; n < 4; ++n) b[n] = *(const bf16x8*)&Bs[wc * 64 + n * 16 + r16][kk + g8];
        #pragma unroll
        for (int m = 0; m < 4; ++m)
          #pragma unroll
          for (int n = 0; n < 4; ++n)
            acc[m][n] = __builtin_amdgcn_mfma_f32_16x16x32_bf16(a[m], b[n], acc[m][n], 0, 0, 0);
      }
    }
    // dump scores (transposed [q][row]) and scan, two 64-row passes
    #pragma unroll
    for (int p = 0; p < 2; ++p) {
      __syncthreads();
      if (wr == p) {
        #pragma unroll
        for (int n = 0; n < 4; ++n) {
          int c = wc * 64 + n * 16 + r16;
          #pragma unroll
          for (int m = 0; m < 4; ++m) {
            int rl = m * 16 + (lane >> 4) * 4;
            #pragma unroll
            for (int j = 0; j < 4; ++j) Sc[c][rl + j] = acc[m][n][j];
          }
        }
      }
      __syncthreads();
      int rbase = mt * 128 + p * 64 + seg * 32;
      #pragma unroll 4
      for (int j = 0; j < 32; ++j) {
        int rr = rbase + j;
        float v = Sc[q][seg * 32 + j];
        if (rr < nvalid) ins10(v, grow0 + rr, s10, id10);
      }
    }
  }
  // merge seg pairs, emit candidates
  __syncthreads();
  float* scf = &Sc[0][0];
  #pragma unroll
  for (int k = 0; k < 10; ++k) {
    scf[tid * 20 + k] = s10[k];
    scf[tid * 20 + 10 + k] = __int_as_float(id10[k]);
  }
  __syncthreads();
  if (tid < 128) {
    int pb = (tid + 128) * 20;
    #pragma unroll
    for (int k = 0; k < 10; ++k) {
      float v = scf[pb + k];
      int ip = __float_as_int(scf[pb + 10 + k]);
      ins10(v, ip, s10, id10);
    }
    float2* cp = cand + ((size_t)(hh * QS + qbase + tid) * NCH + ck) * KTOP;
    #pragma unroll
    for (int k = 0; k < 10; ++k) cp[k] = make_float2(s10[k], __int_as_float(id10[k]));
  }
}

// ---- phase 2: exact top-10 merge, softmax, z_q, vq sums, idx emit ----
__global__ __launch_bounds__(256) void k_topk(
    const float2* __restrict__ cand, const float* __restrict__ cb,
    const float* __restrict__ rn, const float* __restrict__ ZF,
    const float* __restrict__ PT, const float* __restrict__ PG,
    float* __restrict__ out, int* __restrict__ app, float* __restrict__ accs) {
  int wave = threadIdx.x >> 6, lane = threadIdx.x & 63;
  int lq = blockIdx.x * 4 + wave;
  int g = lq >> 9, i = lq & 511;
  int slotA = (g == 0) ? i : (g == 1) ? 512 + i : 1024 + i;
  int halfA = (g == 3) ? 1 : 0;
  int n = (g <= 1) ? 980 : 490;
  const float2* baseA = cand + (size_t)(halfA * QS + slotA) * NCH * KTOP;
  const float2* baseB = cand + (size_t)(QS + slotA) * NCH * KTOP;

  float v[16]; int idv[16];
  #pragma unroll
  for (int j = 0; j < 16; ++j) {
    int c = lane + 64 * j;
    float2 e = make_float2(-3.4e38f, 0.f);
    if (c < n) e = (c < 490) ? baseA[c] : baseB[c - 490];
    v[j] = e.x; idv[j] = __float_as_int(e.y);
  }
  unsigned mask = 0xFFFFu;
  float s10[10]; int id10[10];
  #pragma unroll
  for (int r = 0; r < 10; ++r) {
    float bv = -3.4e38f; int bcb = 0x7fffffff; int bpk = 0;
    #pragma unroll
    for (int j = 0; j < 16; ++j) {
      bool alive = (mask >> j) & 1u;
      float vv = alive ? v[j] : -3.4e38f;
      bool take = (vv > bv) || (alive && vv == bv && idv[j] < bcb);
      if (take) { bv = vv; bcb = idv[j]; bpk = (lane << 5) | j; }
    }
    #pragma unroll
    for (int off = 1; off < 64; off <<= 1) {
      float ov = __shfl_xor(bv, off);
      int ocb = __shfl_xor(bcb, off);
      int opk = __shfl_xor(bpk, off);
      bool take = (ov > bv) || (ov == bv && ocb < bcb);
      if (take) { bv = ov; bcb = ocb; bpk = opk; }
    }
    s10[r] = bv; id10[r] = bcb;
    if ((bpk >> 5) == lane) mask &= ~(1u << (bpk & 31u));
  }
  float smax = s10[0];
  float w[10], wsum = 0.f, rnv[10];
  #pragma unroll
  for (int r = 0; r < 10; ++r) { w[r] = expf(2.0f * (s10[r] - smax)); wsum += w[r]; }
  float inv = 1.0f / wsum;
  #pragma unroll
  for (int r = 0; r < 10; ++r) { w[r] *= inv; rnv[r] = rn[id10[r]]; }

  const float* zrow = (g == 0) ? ZF + (size_t)i * EDIM
                    : (g == 1) ? ZF + (size_t)(512 + i) * EDIM
                    : (g == 2) ? PT + (size_t)i * EDIM
                               : PG + (size_t)i * EDIM;
  size_t obase = (size_t)((g == 0) ? O_ZQT : (g == 1) ? O_ZQG : (g == 2) ? O_SQT : O_SQG)
               + (size_t)i * EDIM;
  float vsum = 0.f;
  #pragma unroll
  for (int j = 0; j < 12; ++j) {
    int d = lane + 64 * j;
    float zq = 0.f;
    #pragma unroll
    for (int r = 0; r < 10; ++r) zq += w[r] * cb[(size_t)id10[r] * EDIM + d] * rnv[r];
    out[obase + d] = zq;
    float df = zq - zrow[d];
    vsum += df * df;
  }
  #pragma unroll
  for (int off = 32; off; off >>= 1) vsum += __shfl_xor(vsum, off);
  if (lane == 0) atomicAdd(&accs[g], vsum);
  if (lane < 10) {
    int val = id10[lane];
    if (g == 0)      app[i * 20 + lane] = val;
    else if (g == 1) app[i * 20 + 10 + lane] = val;
    else if (g == 2) app[10240 + i * 10 + lane] = val;
    else             app[15360 + i * 10 + lane] = val - 50000;
  }
}

// ---- usage: scatter flags over the 3 shifted buffers ----
__global__ __launch_bounds__(256) void k_scatter(
    const int* __restrict__ buf0, const int* __restrict__ app, int* __restrict__ flags) {
  int id = blockIdx.x * 256 + threadIdx.x;
  if (id >= 900000) return;
  int vvar = id / 300000;
  int j = id - vvar * 300000;
  int off = 10240 + 5120 * vvar;
  int keep = 300000 - off;
  int val = (j < keep) ? buf0[off + j] : app[j - keep];
  if (val >= 0 && val < NE_) flags[vvar * NE_ + val] = 1;
}

__global__ __launch_bounds__(256) void k_count(const int* __restrict__ flags, int* __restrict__ cnt) {
  int vvar = blockIdx.y;
  int base = blockIdx.x * 1024;
  int s = 0;
  for (int j = threadIdx.x; j < 1024; j += 256) {
    int idx = base + j;
    if (idx < NE_) s += flags[vvar * NE_ + idx];
  }
  #pragma unroll
  for (int off = 32; off; off >>= 1) s += __shfl_xor(s, off);
  __shared__ int ls[4];
  if ((threadIdx.x & 63) == 0) ls[threadIdx.x >> 6] = s;
  __syncthreads();
  if (threadIdx.x == 0) atomicAdd(&cnt[vvar], ls[0] + ls[1] + ls[2] + ls[3]);
}

__global__ void k_fin(const float* __restrict__ accs, const int* __restrict__ cnt,
                      float* __restrict__ out) {
  if (threadIdx.x == 0) {
    const float inv = 1.0f / (512.0f * 768.0f);
    float vt = accs[0] * inv, vg = accs[1] * inv;
    float vpt = accs[2] * inv, vpg = accs[3] * inv;
    out[O_SVQ]      = vt + vg;
    out[O_SVQ + 1]  = 0.25f * (vt + vg);
    out[O_SVQT]     = vpt;
    out[O_SVQT + 1] = 0.25f * vpt;
    out[O_SVQG]     = vpg;
    out[O_SVQG + 1] = 0.25f * vpg;
    out[O_USE]      = (float)cnt[0] / 100000.0f;
    out[O_USE + 1]  = (float)cnt[1] / 100000.0f;
    out[O_USE + 2]  = (float)cnt[2] / 100000.0f;
  }
}

extern "C" void kernel_launch(void* const* d_in, const int* in_sizes, int n_in,
                              void* d_out, int out_size, void* d_ws, size_t ws_size,
                              hipStream_t stream) {
  const float* z   = (const float*)d_in[0];
  const float* tf  = (const float*)d_in[1];
  const float* gf  = (const float*)d_in[2];
  const float* cb  = (const float*)d_in[4];
  const float* Wv  = (const float*)d_in[5];
  const float* bv  = (const float*)d_in[6];
  const float* Wo  = (const float*)d_in[7];
  const float* bo  = (const float*)d_in[8];
  const float* Wpt = (const float*)d_in[9];
  const float* bpt = (const float*)d_in[10];
  const float* Wpg = (const float*)d_in[11];
  const float* bpg = (const float*)d_in[12];
  const int* used  = (const int*)d_in[13];
  float* out = (float*)d_out;
  char* ws = (char*)d_ws;
  if (ws_size < WS_NEED) return;

  float* rn    = (float*)(ws + RN_OFF);
  short* Q     = (short*)(ws + Q_OFF);
  float* Y     = (float*)(ws + Y_OFF);
  float* ZF    = (float*)(ws + ZF_OFF);
  float* PT    = (float*)(ws + PT_OFF);
  float* PG    = (float*)(ws + PG_OFF);
  float2* cand = (float2*)(ws + CAND_OFF);
  int* app     = (int*)(ws + APP_OFF);
  int* flags   = (int*)(ws + FLAG_OFF);
  int* cnt     = (int*)(ws + CNT_OFF);
  float* accs  = (float*)(ws + ACC_OFF);

  hipMemsetAsync(ws + FLAG_OFF, 0, 1200128, stream);
  k_rnorm<<<25000, 256, 0, stream>>>(cb, rn);
  k_copyz<<<384, 256, 0, stream>>>(z, out);
  // z_flat_text = oproj(vproj(graph)), z_flat_graph = oproj(vproj(text))
  k_gemm_proj<<<dim3(4, 6), 256, 0, stream>>>(gf, 768, Wv, bv, Y);
  k_gemm_proj<<<dim3(4, 6), 256, 0, stream>>>(tf, 768, Wv, bv, Y + 512 * 768);
  k_gemm_proj<<<dim3(8, 6), 256, 0, stream>>>(Y, 768, Wo, bo, ZF);
  k_gemm_proj<<<dim3(4, 6), 256, 0, stream>>>(z, 1536, Wpt, bpt, PT);
  k_gemm_proj<<<dim3(4, 6), 256, 0, stream>>>(z + 768, 1536, Wpg, bpg, PG);
  k_normq<<<512, 256, 0, stream>>>(ZF, PT, PG, Q);
  k_scores<<<dim3(NQT, NCH, 2), 256, 0, stream>>>(cb, rn, Q, cand);
  k_topk<<<512, 256, 0, stream>>>(cand, cb, rn, ZF, PT, PG, out, app, accs);
  k_scatter<<<3516, 256, 0, stream>>>(used, app, flags);
  k_count<<<dim3(98, 3), 256, 0, stream>>>(flags, cnt);
  k_fin<<<1, 64, 0, stream>>>(accs, cnt, out);
}